// Round 1
// baseline (67.939 us; speedup 1.0000x reference)
//
#include <hip/hip_runtime.h>

// Problem constants (match reference)
constexpr int Bc = 64;
constexpr int Nc = 32768;
constexpr int Kc = 128;
constexpr int Tc = 512;      // trajectory length
constexpr int TMAXc = 512;   // table time dim (== Tc)
constexpr long long BN  = (long long)Bc * Nc;       // 2,097,152
constexpr long long BKT = (long long)Bc * Kc * Tc;  // 4,194,304

// ---------------- Phase 1: scatter traj xy into (B,K,TMAX,2) table ----------
// times is a permutation of 0..511 per (b,k), so every slot is written.
__global__ __launch_bounds__(256) void build_table_k(
    const float* __restrict__ traj,   // (B,K,T,5)
    float2* __restrict__ table)       // (B,K,TMAX) of float2
{
    long long i = (long long)blockIdx.x * 256 + threadIdx.x;  // over B*K*T
    if (i >= BKT) return;
    const float* p = traj + i * 5;
    float x  = p[0];
    float y  = p[1];
    float tv = p[4];
    int tau = __float2int_rn(tv * 10.0f);   // matches jnp.round(...)
    long long bk = i >> 9;                  // / Tc (512)
    if ((unsigned)tau < (unsigned)TMAXc) {  // mode='drop' semantics
        table[(bk << 9) + tau] = make_float2(x, y);
    }
}

// ---------------- Phase 2: gather + per-block partial reduction -------------
__global__ __launch_bounds__(256) void gather_reduce_k(
    const float4* __restrict__ state,   // (B,N,4)
    const int*    __restrict__ tidx,    // (B,N)
    const int*    __restrict__ uid,     // (B,N)
    const float2* __restrict__ table,   // (B,K,TMAX)
    float2*       __restrict__ partials)
{
    int i = blockIdx.x * 256 + threadIdx.x;   // over B*N (grid sized exactly)
    float4 s = state[i];
    int id = uid[i];
    int ti = tidx[i];
    int b  = i >> 15;                          // / Nc (32768)

    float sum = 0.0f, cnt = 0.0f;
    if (id >= 0) {
        int obj = min(id, Kc - 1);             // clip(unique_ids, 0, K-1)
        int tcl = min(max(ti, 0), TMAXc - 1);  // clip(time_idx, 0, TMAX-1)
        float2 tg = table[(((long long)b * Kc + obj) << 9) + tcl];
        sum = fabsf(s.x - tg.x) + fabsf(s.y - tg.y);
        cnt = 1.0f;
    }

    // wave64 butterfly-free down-reduce
    #pragma unroll
    for (int off = 32; off > 0; off >>= 1) {
        sum += __shfl_down(sum, off, 64);
        cnt += __shfl_down(cnt, off, 64);
    }
    __shared__ float2 lds[4];
    int lane = threadIdx.x & 63;
    int w    = threadIdx.x >> 6;
    if (lane == 0) lds[w] = make_float2(sum, cnt);
    __syncthreads();
    if (threadIdx.x == 0) {
        float s2 = 0.0f, c2 = 0.0f;
        #pragma unroll
        for (int j = 0; j < 4; ++j) { s2 += lds[j].x; c2 += lds[j].y; }
        partials[blockIdx.x] = make_float2(s2, c2);
    }
}

// ---------------- Phase 3: deterministic final reduce -> loss ---------------
__global__ __launch_bounds__(1024) void final_reduce_k(
    const float2* __restrict__ partials, int n, float* __restrict__ out)
{
    float s = 0.0f, c = 0.0f;
    for (int j = threadIdx.x; j < n; j += 1024) {
        float2 p = partials[j];
        s += p.x; c += p.y;
    }
    #pragma unroll
    for (int off = 32; off > 0; off >>= 1) {
        s += __shfl_down(s, off, 64);
        c += __shfl_down(c, off, 64);
    }
    __shared__ float2 lds[16];
    int lane = threadIdx.x & 63;
    int w    = threadIdx.x >> 6;
    if (lane == 0) lds[w] = make_float2(s, c);
    __syncthreads();
    if (threadIdx.x == 0) {
        float s2 = 0.0f, c2 = 0.0f;
        #pragma unroll
        for (int j = 0; j < 16; ++j) { s2 += lds[j].x; c2 += lds[j].y; }
        out[0] = s2 / c2;
    }
}

extern "C" void kernel_launch(void* const* d_in, const int* in_sizes, int n_in,
                              void* d_out, int out_size, void* d_ws, size_t ws_size,
                              hipStream_t stream) {
    const float4* state = (const float4*)d_in[0];   // (B,N,4) f32
    const int*    tidx  = (const int*)  d_in[1];    // (B,N)   i32
    const int*    uid   = (const int*)  d_in[2];    // (B,N)   i32
    const float*  traj  = (const float*)d_in[3];    // (B,K,T,5) f32
    float* out = (float*)d_out;

    // workspace layout: [table: B*K*TMAX*2 f32 = 33,554,432 B][partials: 8192*float2]
    float2* table    = (float2*)d_ws;
    float2* partials = (float2*)((char*)d_ws + (size_t)Bc * Kc * TMAXc * 2 * sizeof(float));

    constexpr int nblk1 = (int)(BKT / 256);  // 16384
    constexpr int nblk2 = (int)(BN  / 256);  // 8192

    build_table_k  <<<nblk1, 256, 0, stream>>>(traj, table);
    gather_reduce_k<<<nblk2, 256, 0, stream>>>(state, tidx, uid, table, partials);
    final_reduce_k <<<1, 1024, 0, stream>>>(partials, nblk2, out);
}

// Round 3
// 56.934 us; speedup vs baseline: 1.1933x; 1.1933x over previous
//
#include <hip/hip_runtime.h>

// Problem constants (match reference)
constexpr int Bc = 64;
constexpr int Nc = 32768;
constexpr int Kc = 128;
constexpr int Tc = 512;      // trajectory length
constexpr int TMAXc = 512;   // table time dim (== Tc)
constexpr long long BN  = (long long)Bc * Nc;       // 2,097,152
constexpr int BK = Bc * Kc;                         // 8192

typedef float  f32x4 __attribute__((ext_vector_type(4)));
typedef int    i32x1 __attribute__((ext_vector_type(1)));

// ---------------- Phase 1: scatter traj xy into (B,K,TMAX,2) table ----------
// One block per (b,k). Coalesced float4 load of the 2560-float traj slice
// into LDS, scatter into a 4 KB LDS table slice, coalesced float4 store out.
// times is a permutation of 0..511 per (b,k), so every slot is written.
__global__ __launch_bounds__(256) void build_table_k(
    const float4* __restrict__ traj4,   // (B,K,T,5) viewed as float4[BK*640]
    float4* __restrict__ table4)        // (B,K,TMAX,2) viewed as float4[BK*256]
{
    __shared__ __align__(16) float stage[Tc * 5];   // 10240 B
    __shared__ __align__(16) float2 tbl[TMAXc];     //  4096 B

    const int bk = blockIdx.x;
    const float4* src = traj4 + (size_t)bk * 640;

    // coalesced load: 640 float4 per block
    for (int j = threadIdx.x; j < 640; j += 256) {
        ((float4*)stage)[j] = src[j];
    }
    __syncthreads();

    // scatter within LDS
    #pragma unroll
    for (int r = 0; r < 2; ++r) {
        int t = threadIdx.x + r * 256;
        float x  = stage[t * 5 + 0];
        float y  = stage[t * 5 + 1];
        float tv = stage[t * 5 + 4];
        int tau = __float2int_rn(tv * 10.0f);      // matches jnp.round(...)
        if ((unsigned)tau < (unsigned)TMAXc) {     // mode='drop'
            tbl[tau] = make_float2(x, y);
        }
    }
    __syncthreads();

    // coalesced store: 256 float4 (= 512 float2) per block
    table4[(size_t)bk * 256 + threadIdx.x] = ((const float4*)tbl)[threadIdx.x];
}

// ---------------- Phase 2: gather + per-block partial reduction -------------
__global__ __launch_bounds__(256) void gather_reduce_k(
    const f32x4*  __restrict__ state,   // (B,N,4)
    const int*    __restrict__ tidx,    // (B,N)
    const int*    __restrict__ uid,     // (B,N)
    const float2* __restrict__ table,   // (B,K,TMAX)
    float2*       __restrict__ partials)
{
    float sum = 0.0f, cnt = 0.0f;

    #pragma unroll
    for (int r = 0; r < 4; ++r) {
        int i = (r * 2048 + blockIdx.x) * 256 + threadIdx.x;  // over B*N
        f32x4 s = __builtin_nontemporal_load(&state[i]);
        int id = __builtin_nontemporal_load(&uid[i]);
        int ti = __builtin_nontemporal_load(&tidx[i]);
        int b  = i >> 15;                          // / Nc

        if (id >= 0) {
            int obj = min(id, Kc - 1);             // clip(unique_ids, 0, K-1)
            int tcl = min(max(ti, 0), TMAXc - 1);  // clip(time_idx, 0, TMAX-1)
            float2 tg = table[(((long long)b * Kc + obj) << 9) + tcl];
            sum += fabsf(s.x - tg.x) + fabsf(s.y - tg.y);
            cnt += 1.0f;
        }
    }

    // wave64 down-reduce
    #pragma unroll
    for (int off = 32; off > 0; off >>= 1) {
        sum += __shfl_down(sum, off, 64);
        cnt += __shfl_down(cnt, off, 64);
    }
    __shared__ float2 lds[4];
    int lane = threadIdx.x & 63;
    int w    = threadIdx.x >> 6;
    if (lane == 0) lds[w] = make_float2(sum, cnt);
    __syncthreads();
    if (threadIdx.x == 0) {
        float s2 = 0.0f, c2 = 0.0f;
        #pragma unroll
        for (int j = 0; j < 4; ++j) { s2 += lds[j].x; c2 += lds[j].y; }
        partials[blockIdx.x] = make_float2(s2, c2);
    }
}

// ---------------- Phase 3: deterministic final reduce -> loss ---------------
__global__ __launch_bounds__(1024) void final_reduce_k(
    const float2* __restrict__ partials, int n, float* __restrict__ out)
{
    float s = 0.0f, c = 0.0f;
    for (int j = threadIdx.x; j < n; j += 1024) {
        float2 p = partials[j];
        s += p.x; c += p.y;
    }
    #pragma unroll
    for (int off = 32; off > 0; off >>= 1) {
        s += __shfl_down(s, off, 64);
        c += __shfl_down(c, off, 64);
    }
    __shared__ float2 lds[16];
    int lane = threadIdx.x & 63;
    int w    = threadIdx.x >> 6;
    if (lane == 0) lds[w] = make_float2(s, c);
    __syncthreads();
    if (threadIdx.x == 0) {
        float s2 = 0.0f, c2 = 0.0f;
        #pragma unroll
        for (int j = 0; j < 16; ++j) { s2 += lds[j].x; c2 += lds[j].y; }
        out[0] = s2 / c2;
    }
}

extern "C" void kernel_launch(void* const* d_in, const int* in_sizes, int n_in,
                              void* d_out, int out_size, void* d_ws, size_t ws_size,
                              hipStream_t stream) {
    const f32x4*  state = (const f32x4*)d_in[0];    // (B,N,4) f32
    const int*    tidx  = (const int*)  d_in[1];    // (B,N)   i32
    const int*    uid   = (const int*)  d_in[2];    // (B,N)   i32
    const float4* traj4 = (const float4*)d_in[3];   // (B,K,T,5) f32
    float* out = (float*)d_out;

    // workspace layout: [table: B*K*TMAX*2 f32 = 33,554,432 B][partials: 2048*float2]
    float2* table    = (float2*)d_ws;
    float2* partials = (float2*)((char*)d_ws + (size_t)Bc * Kc * TMAXc * 2 * sizeof(float));

    build_table_k  <<<BK, 256, 0, stream>>>(traj4, (float4*)table);
    gather_reduce_k<<<2048, 256, 0, stream>>>(state, tidx, uid, table, partials);
    final_reduce_k <<<1, 1024, 0, stream>>>(partials, 2048, out);
}